// Round 3
// baseline (85.927 us; speedup 1.0000x reference)
//
#include <hip/hip_runtime.h>
#include <hip/hip_bf16.h>
#include <cstdint>
#include <cstddef>

#define VOCAB   32000
#define HIDDEN  1024
#define BATCH   128
#define SEQ     2048
#define NEG_INF -1.0e9f

#define BN 128
#define BK 64
#define NT 8      // N tiles (1024/128)
#define KG 64     // split-K groups -> 512 workgroups = 2/CU

typedef __attribute__((ext_vector_type(8))) short  short8;
typedef __attribute__((ext_vector_type(4))) float  f32x4;

union BF2 { __hip_bfloat162 h; uint32_t u; };
static __device__ __forceinline__ uint32_t pk2(float lo, float hi) {
  BF2 c; c.h = __float22bfloat162_rn(make_float2(lo, hi));  // v_cvt_pk_bf16_f32 (RNE)
  return c.u;
}
union S8U4 { short8 s; uint32_t u[4]; };
static __device__ __forceinline__ short8 pack8(const float* f) {
  S8U4 r;
  r.u[0] = pk2(f[0], f[1]); r.u[1] = pk2(f[2], f[3]);
  r.u[2] = pk2(f[4], f[5]); r.u[3] = pk2(f[6], f[7]);
  return r.s;
}
static __device__ __forceinline__ float bf2f(ushort u) {
  return __uint_as_float(((uint32_t)u) << 16);
}

// ---------------------------------------------------------------------------
// Kernel A: fused {zero own pooled row} + masked softmax + row-local scatter.
// Scatter from batch row b only touches pooled row b, so the zero can be
// fused; the reduction __syncthreads orders zero-before-atomics.
// ---------------------------------------------------------------------------
__global__ __launch_bounds__(1024) void softmax_scatter_kernel(
    const int* __restrict__ x, const float* __restrict__ w_attn,
    const float* __restrict__ b_attn, float* __restrict__ pooled) {
  const int b = blockIdx.x, tid = threadIdx.x;
  float* pr = pooled + (size_t)b * VOCAB;
  float4* pr4 = (float4*)pr;
  for (int i = tid; i < VOCAB / 4; i += 1024) pr4[i] = (float4){0.f, 0.f, 0.f, 0.f};

  const int* xr = x + (size_t)b * SEQ;
  const float ba = b_attn[0];
  int xi[2]; float lg[2];
  float m = -3.0e38f;
#pragma unroll
  for (int i = 0; i < 2; ++i) {
    int t = xr[tid + 1024 * i];
    xi[i] = t;
    float v = (t > 0) ? (w_attn[t] + ba) : NEG_INF;
    lg[i] = v;
    m = fmaxf(m, v);
  }
#pragma unroll
  for (int off = 32; off; off >>= 1) m = fmaxf(m, __shfl_xor(m, off));
  __shared__ float red[16], red2[16];
  if ((tid & 63) == 0) red[tid >> 6] = m;
  __syncthreads();                      // also orders zero-loop before atomics
  float M = red[0];
#pragma unroll
  for (int i = 1; i < 16; ++i) M = fmaxf(M, red[i]);

  float e[2], s = 0.f;
#pragma unroll
  for (int i = 0; i < 2; ++i) {
    float v = (xi[i] > 0) ? __expf(lg[i] - M) : 0.f;
    e[i] = v; s += v;
  }
#pragma unroll
  for (int off = 32; off; off >>= 1) s += __shfl_xor(s, off);
  if ((tid & 63) == 0) red2[tid >> 6] = s;
  __syncthreads();
  float S = 0.f;
#pragma unroll
  for (int i = 0; i < 16; ++i) S += red2[i];
  const float inv = 1.0f / S;
#pragma unroll
  for (int i = 0; i < 2; ++i)
    if (xi[i] > 0) atomicAdd(pr + xi[i], e[i] * inv);
}

// ---------------------------------------------------------------------------
// Kernel B: split-K bf16 MFMA GEMM, 128x128 tile, 4 waves (2x2).
//  - B tile: LDS, XOR-swizzled (oct ^= n&7), conflict-free b128 write+read.
//    Staged n-coalesced (scalar dword loads), double-buffered, T14 split:
//    issue loads -> compute -> cvt+write -> barrier.
//  - A fragments: direct from global (pooled is L2/L3-hot), v_cvt_pk pack.
// ---------------------------------------------------------------------------
template <bool ATOMIC>
__global__ __launch_bounds__(256, 2) void gemm_kernel(
    const float* __restrict__ pooled, const float* __restrict__ w1,
    void* __restrict__ hout_v) {
  const int tid  = threadIdx.x;
  const int lane = tid & 63;
  const int wid  = tid >> 6;
  const int bid  = blockIdx.x;
  const int nt   = bid & 7;
  const int g    = bid >> 3;
  const int n0   = nt * BN;

  int kb, ke;                      // 500 K-tiles: 52 groups of 8, 12 of 7
  if (g < 52) { kb = g * 8;              ke = kb + 8; }
  else        { kb = 416 + (g - 52) * 7; ke = kb + 7; }

  // ushort index = n*BK + (k ^ ((n&7)<<3)); byte-level: ^ ((n&7)<<4)
  __shared__ __align__(16) ushort Bs[2][BN * BK];   // 2 x 16 KiB

  const int wm = wid >> 1, wn = wid & 1;
  const int fr = lane & 15, fq = lane >> 4;

  f32x4 acc[4][4];
#pragma unroll
  for (int i = 0; i < 4; ++i)
#pragma unroll
    for (int j = 0; j < 4; ++j) acc[i][j] = (f32x4){0.f, 0.f, 0.f, 0.f};

  // staging: thread owns column n = tid&127, k-octs (tid>>7)*32 + i*8
  const int sn  = tid & 127;
  const int sk0 = (tid >> 7) * 32;
  const float* w1base = w1 + n0 + sn;
  const int swz_w = (sn & 7) << 3;

  float sreg[32];

  auto issue_loads = [&](int kt) {
    const float* src = w1base + (size_t)(kt * BK + sk0) * HIDDEN;
#pragma unroll
    for (int i = 0; i < 32; ++i) sreg[i] = src[(size_t)i * HIDDEN];
  };
  auto write_tile = [&](int buf) {
    ushort* dst = &Bs[buf][sn * BK];
#pragma unroll
    for (int i = 0; i < 4; ++i) {
      short8 v = pack8(&sreg[i * 8]);
      *(short8*)(dst + ((sk0 + i * 8) ^ swz_w)) = v;
    }
  };
  auto compute = [&](int buf, int k0) {
    short8 af0[4], af1[4], bf0[4], bf1[4];
#pragma unroll
    for (int mi = 0; mi < 4; ++mi) {
      const int row = wm * 64 + mi * 16 + fr;
      const float* ap = pooled + (size_t)row * VOCAB + k0 + fq * 8;
      float a[8], c[8];
      *(float4*)&a[0] = *(const float4*)ap;
      *(float4*)&a[4] = *(const float4*)(ap + 4);
      *(float4*)&c[0] = *(const float4*)(ap + 32);
      *(float4*)&c[4] = *(const float4*)(ap + 36);
      af0[mi] = pack8(a);
      af1[mi] = pack8(c);
    }
    const ushort* base = &Bs[buf][0];
#pragma unroll
    for (int ni = 0; ni < 4; ++ni) {
      const int n = wn * 64 + ni * 16 + fr;
      const ushort* rp = base + n * BK;
      const int swz = (n & 7) << 3;
      bf0[ni] = *(const short8*)(rp + ((fq * 8) ^ swz));
      bf1[ni] = *(const short8*)(rp + ((32 + fq * 8) ^ swz));
    }
#pragma unroll
    for (int mi = 0; mi < 4; ++mi)
#pragma unroll
      for (int ni = 0; ni < 4; ++ni)
        acc[mi][ni] = __builtin_amdgcn_mfma_f32_16x16x32_bf16(
            af0[mi], bf0[ni], acc[mi][ni], 0, 0, 0);
#pragma unroll
    for (int mi = 0; mi < 4; ++mi)
#pragma unroll
      for (int ni = 0; ni < 4; ++ni)
        acc[mi][ni] = __builtin_amdgcn_mfma_f32_16x16x32_bf16(
            af1[mi], bf1[ni], acc[mi][ni], 0, 0, 0);
  };

  issue_loads(kb);
  write_tile(0);
  __syncthreads();
  int cur = 0;
  for (int kt = kb; kt < ke; ++kt) {
    const bool more = (kt + 1 < ke);
    if (more) issue_loads(kt + 1);       // loads in flight across compute
    compute(cur, kt * BK);
    if (more) write_tile(cur ^ 1);       // waits vmcnt, writes other buffer
    __syncthreads();
    cur ^= 1;
  }

  // epilogue: C/D mapping col = lane&15, row = (lane>>4)*4 + r  [m89-verified]
#pragma unroll
  for (int mi = 0; mi < 4; ++mi) {
#pragma unroll
    for (int ni = 0; ni < 4; ++ni) {
      const int col = n0 + wn * 64 + ni * 16 + fr;
#pragma unroll
      for (int r = 0; r < 4; ++r) {
        const int row = wm * 64 + mi * 16 + fq * 4 + r;
        if (ATOMIC) {
          atomicAdd((float*)hout_v + (size_t)row * HIDDEN + col,
                    acc[mi][ni][r]);
        } else {
          union { ushort u; __hip_bfloat16 b; } cv;
          cv.b = __float2bfloat16(acc[mi][ni][r]);
          ((ushort*)hout_v)[((size_t)g * BATCH + row) * HIDDEN + col] = cv.u;
        }
      }
    }
  }
}

// ---------------------------------------------------------------------------
// Kernel C: h = relu(sum_p parts + b1); out = log_softmax(h @ w2 + b2)
// 128 blocks x 512 threads; 16B/lane partial reads, LDS combine across p-quads.
// ---------------------------------------------------------------------------
__global__ __launch_bounds__(512) void finalize_kernel(
    const ushort* __restrict__ parts, const float* __restrict__ b1,
    const float* __restrict__ w2, const float* __restrict__ b2,
    float* __restrict__ out) {
  const int b = blockIdx.x, tid = threadIdx.x;
  const int jq = tid & 127;     // j block of 8 -> j0 = jq*8
  const int ph = tid >> 7;      // p quarter: p in [ph*16, ph*16+16)
  float h[8] = {0.f, 0.f, 0.f, 0.f, 0.f, 0.f, 0.f, 0.f};
  const ushort* src =
      parts + ((size_t)(ph * 16) * BATCH + b) * HIDDEN + jq * 8;
#pragma unroll
  for (int p = 0; p < 16; ++p) {
    short8 v = *(const short8*)(src + (size_t)p * BATCH * HIDDEN);
#pragma unroll
    for (int e = 0; e < 8; ++e) h[e] += bf2f((ushort)v[e]);
  }
  __shared__ float hp[4][HIDDEN];
  *(f32x4*)&hp[ph][jq * 8]     = (f32x4){h[0], h[1], h[2], h[3]};
  *(f32x4*)&hp[ph][jq * 8 + 4] = (f32x4){h[4], h[5], h[6], h[7]};
  __syncthreads();

  float s0 = 0.f, s1 = 0.f;
#pragma unroll
  for (int r = 0; r < 2; ++r) {
    const int j = tid * 2 + r;
    float hv = hp[0][j] + hp[1][j] + hp[2][j] + hp[3][j] + b1[j];
    hv = fmaxf(hv, 0.f);
    float2 w = *(const float2*)(w2 + 2 * j);
    s0 += hv * w.x;
    s1 += hv * w.y;
  }
#pragma unroll
  for (int off = 32; off; off >>= 1) {
    s0 += __shfl_xor(s0, off);
    s1 += __shfl_xor(s1, off);
  }
  __shared__ float r0[8], r1[8];
  if ((tid & 63) == 0) { r0[tid >> 6] = s0; r1[tid >> 6] = s1; }
  __syncthreads();
  if (tid == 0) {
    float l0 = b2[0], l1 = b2[1];
#pragma unroll
    for (int i = 0; i < 8; ++i) { l0 += r0[i]; l1 += r1[i]; }
    float mx = fmaxf(l0, l1);
    float lse = mx + logf(__expf(l0 - mx) + __expf(l1 - mx));
    out[2 * b]     = l0 - lse;
    out[2 * b + 1] = l1 - lse;
  }
}

// f32 fallback finalize (small-ws atomic path)
__global__ __launch_bounds__(256) void finalize_f32_kernel(
    const float* __restrict__ hbuf, const float* __restrict__ b1,
    const float* __restrict__ w2, const float* __restrict__ b2,
    float* __restrict__ out) {
  const int b = blockIdx.x, tid = threadIdx.x;
  const int j0 = tid * 4;
  float4 h = *(const float4*)(hbuf + ((size_t)b << 10) + j0);
  float hv0 = fmaxf(h.x + b1[j0 + 0], 0.f);
  float hv1 = fmaxf(h.y + b1[j0 + 1], 0.f);
  float hv2 = fmaxf(h.z + b1[j0 + 2], 0.f);
  float hv3 = fmaxf(h.w + b1[j0 + 3], 0.f);
  float4 wa = *(const float4*)(w2 + 2 * j0);
  float4 wb = *(const float4*)(w2 + 2 * j0 + 4);
  float s0 = hv0 * wa.x + hv1 * wa.z + hv2 * wb.x + hv3 * wb.z;
  float s1 = hv0 * wa.y + hv1 * wa.w + hv2 * wb.y + hv3 * wb.w;
#pragma unroll
  for (int off = 32; off; off >>= 1) {
    s0 += __shfl_xor(s0, off);
    s1 += __shfl_xor(s1, off);
  }
  __shared__ float r0[4], r1[4];
  if ((tid & 63) == 0) { r0[tid >> 6] = s0; r1[tid >> 6] = s1; }
  __syncthreads();
  if (tid == 0) {
    float l0 = r0[0] + r0[1] + r0[2] + r0[3] + b2[0];
    float l1 = r1[0] + r1[1] + r1[2] + r1[3] + b2[1];
    float mx = fmaxf(l0, l1);
    float lse = mx + logf(__expf(l0 - mx) + __expf(l1 - mx));
    out[2 * b]     = l0 - lse;
    out[2 * b + 1] = l1 - lse;
  }
}

__global__ __launch_bounds__(256) void zero_kernel(float4* __restrict__ p,
                                                   int n4) {
  int i = blockIdx.x * 256 + threadIdx.x;
  const int stride = gridDim.x * 256;
  for (; i < n4; i += stride) p[i] = (float4){0.f, 0.f, 0.f, 0.f};
}

// ---------------------------------------------------------------------------
extern "C" void kernel_launch(void* const* d_in, const int* in_sizes, int n_in,
                              void* d_out, int out_size, void* d_ws,
                              size_t ws_size, hipStream_t stream) {
  const int*   x      = (const int*)  d_in[0];
  const float* w_attn = (const float*)d_in[1];
  const float* b_attn = (const float*)d_in[2];
  const float* w1     = (const float*)d_in[3];
  const float* b1     = (const float*)d_in[4];
  const float* w2     = (const float*)d_in[5];
  const float* b2     = (const float*)d_in[6];
  float* out = (float*)d_out;

  const size_t pooledBytes = (size_t)BATCH * VOCAB * sizeof(float);         // 16.38 MB
  const size_t partBytes   = (size_t)KG * BATCH * HIDDEN * sizeof(ushort);  // 16.78 MB

  float*  pooled = (float*)d_ws;
  ushort* parts  = (ushort*)((char*)d_ws + pooledBytes);

  if (ws_size >= pooledBytes + partBytes) {
    softmax_scatter_kernel<<<BATCH, 1024, 0, stream>>>(x, w_attn, b_attn,
                                                       pooled);
    gemm_kernel<false><<<NT * KG, 256, 0, stream>>>(pooled, w1, parts);
    finalize_kernel<<<BATCH, 512, 0, stream>>>(parts, b1, w2, b2, out);
  } else {
    float* hbuf = (float*)((char*)d_ws + pooledBytes);
    const size_t hBytes = (size_t)BATCH * HIDDEN * sizeof(float);
    zero_kernel<<<256, 256, 0, stream>>>((float4*)hbuf, (int)(hBytes / 16));
    softmax_scatter_kernel<<<BATCH, 1024, 0, stream>>>(x, w_attn, b_attn,
                                                       pooled);
    gemm_kernel<true><<<NT * KG, 256, 0, stream>>>(pooled, w1, hbuf);
    finalize_f32_kernel<<<BATCH, 256, 0, stream>>>(hbuf, b1, w2, b2, out);
  }
}

// Round 4
// 44.929 us; speedup vs baseline: 1.9125x; 1.9125x over previous
//
#include <hip/hip_runtime.h>
#include <hip/hip_bf16.h>
#include <cstdint>
#include <cstddef>

#define VOCAB   32000
#define HIDDEN  1024
#define BATCH   128
#define SEQ     2048
#define NEG_INF -1.0e9f

#define BN 128
#define BK 64
#define NT 8      // N tiles (1024/128)
#define KG 64     // split-K groups -> 512 blocks = 2/CU

typedef __attribute__((ext_vector_type(8))) short  short8;
typedef __attribute__((ext_vector_type(4))) float  f32x4;

union BF2 { __hip_bfloat162 h; uint32_t u; };
static __device__ __forceinline__ uint32_t pk2(float lo, float hi) {
  BF2 c; c.h = __float22bfloat162_rn(make_float2(lo, hi));  // v_cvt_pk_bf16_f32
  return c.u;
}
union S8U4 { short8 s; uint32_t u[4]; };
static __device__ __forceinline__ short8 pack8(const float* f) {
  S8U4 r;
  r.u[0] = pk2(f[0], f[1]); r.u[1] = pk2(f[2], f[3]);
  r.u[2] = pk2(f[4], f[5]); r.u[3] = pk2(f[6], f[7]);
  return r.s;
}
static __device__ __forceinline__ float bf2f(ushort u) {
  return __uint_as_float(((uint32_t)u) << 16);
}

typedef const uint32_t __attribute__((address_space(1))) gu32;
typedef uint32_t       __attribute__((address_space(3))) lu32;
static __device__ __forceinline__ void g2lds16(const void* g, void* l) {
  __builtin_amdgcn_global_load_lds((gu32*)g, (lu32*)l, 16, 0, 0);
}

// ---------------------------------------------------------------------------
// Kernel A: masked softmax over SEQ + scatter-add into a per-row LDS
// accumulator (VOCAB f32 = 128 KB dynamic LDS), then write row out as bf16.
// Row-local: block b only touches pooled_bf row b. No global f32 pooled, no
// global zero pass, LDS atomics instead of L2 atomics.
// ---------------------------------------------------------------------------
__global__ __launch_bounds__(1024) void softmax_scatter_bf(
    const int* __restrict__ x, const float* __restrict__ w_attn,
    const float* __restrict__ b_attn, ushort* __restrict__ pooled_bf) {
  extern __shared__ float lds[];          // VOCAB floats
  const int b = blockIdx.x, tid = threadIdx.x;
  float4* l4 = (float4*)lds;
  for (int i = tid; i < VOCAB / 4; i += 1024)
    l4[i] = (float4){0.f, 0.f, 0.f, 0.f};

  const int* xr = x + (size_t)b * SEQ;
  const float ba = b_attn[0];
  int xi[2]; float lg[2];
  float m = -3.0e38f;
#pragma unroll
  for (int i = 0; i < 2; ++i) {
    int t = xr[tid + 1024 * i];
    xi[i] = t;
    float v = (t > 0) ? (w_attn[t] + ba) : NEG_INF;
    lg[i] = v;
    m = fmaxf(m, v);
  }
#pragma unroll
  for (int off = 32; off; off >>= 1) m = fmaxf(m, __shfl_xor(m, off));
  __shared__ float red[16], red2[16];
  if ((tid & 63) == 0) red[tid >> 6] = m;
  __syncthreads();                        // also orders zero-loop vs atomics
  float M = red[0];
#pragma unroll
  for (int i = 1; i < 16; ++i) M = fmaxf(M, red[i]);

  float e[2], s = 0.f;
#pragma unroll
  for (int i = 0; i < 2; ++i) {
    float v = (xi[i] > 0) ? __expf(lg[i] - M) : 0.f;
    e[i] = v; s += v;
  }
#pragma unroll
  for (int off = 32; off; off >>= 1) s += __shfl_xor(s, off);
  if ((tid & 63) == 0) red2[tid >> 6] = s;
  __syncthreads();
  float S = 0.f;
#pragma unroll
  for (int i = 0; i < 16; ++i) S += red2[i];
  const float inv = 1.0f / S;
#pragma unroll
  for (int i = 0; i < 2; ++i)
    if (xi[i] > 0) atomicAdd(&lds[xi[i]], e[i] * inv);   // ds_add_f32
  __syncthreads();

  ushort* pr = pooled_bf + (size_t)b * VOCAB;
  for (int i = tid; i < VOCAB / 4; i += 1024) {
    float4 v = l4[i];
    uint2 o = {pk2(v.x, v.y), pk2(v.z, v.w)};
    *(uint2*)(pr + i * 4) = o;
  }
}

// ---------------------------------------------------------------------------
// Kernel B: split-K bf16 MFMA GEMM, 128x128x64 tiles, 4 waves (2x2), T14
// pipelined: issue A(t+1) via global_load_lds (swizzled global source,
// linear LDS dest) + B(t+1) reg loads -> compute(t) -> cvt+write B -> barrier.
// LDS: As/Bs [2][128][64] bf16 (oct ^= row&7 swizzle), 64 KB -> 2 blocks/CU.
// ---------------------------------------------------------------------------
template <bool ATOMIC>
__global__ __launch_bounds__(256, 2) void gemm_kernel(
    const ushort* __restrict__ pooled_bf, const float* __restrict__ w1,
    void* __restrict__ hout_v) {
  const int tid  = threadIdx.x;
  const int lane = tid & 63;
  const int wid  = tid >> 6;
  // XCD swizzle: round-robin dispatch -> XCD x owns g in [x*8, x*8+8), all nt
  const int id2 = (blockIdx.x & 7) * 64 + (blockIdx.x >> 3);
  const int nt  = id2 & 7;
  const int g   = id2 >> 3;
  const int n0  = nt * BN;

  int kb, ke;                       // 500 K-tiles: 52 groups of 8, 12 of 7
  if (g < 52) { kb = g * 8;              ke = kb + 8; }
  else        { kb = 416 + (g - 52) * 7; ke = kb + 7; }

  __shared__ __align__(16) ushort As[2][BN * BK];   // 2 x 16 KiB
  __shared__ __align__(16) ushort Bs[2][BN * BK];

  const int wm = wid >> 1, wn = wid & 1;            // 2x2 waves, 64x64 each
  const int fr = lane & 15, fq = lane >> 4;
  const int x7 = fr & 7;                            // == row&7 == n&7

  f32x4 acc[4][4];
#pragma unroll
  for (int i = 0; i < 4; ++i)
#pragma unroll
    for (int j = 0; j < 4; ++j) acc[i][j] = (f32x4){0.f, 0.f, 0.f, 0.f};

  // A issue: group gi = i*4+wid covers LDS bytes [gi*1024, +1024) = 8 rows.
  // lane granule: row = gi*8 + (lane>>3), oct_sw = lane&7,
  // source oct = (lane&7) ^ (lane>>3)  [inverse swizzle on global side]
  int aoff[4];
#pragma unroll
  for (int i = 0; i < 4; ++i) {
    const int row = (i * 4 + wid) * 8 + (lane >> 3);
    const int oct = (lane & 7) ^ (lane >> 3);
    aoff[i] = row * (VOCAB * 2) + oct * 16;         // bytes
  }
  const char* pbase = (const char*)pooled_bf;

  // B staging: thread owns n in {2*lane, 2*lane+1}, k in [wid*16, wid*16+16)
  const int sn2 = lane * 2;
  const int sk0 = wid * 16;
  float2 v[16];

  auto issueA = [&](int kt, int buf) {
#pragma unroll
    for (int i = 0; i < 4; ++i)
      g2lds16(pbase + aoff[i] + kt * (BK * 2),
              (char*)&As[buf][0] + ((i * 4 + wid) << 10));
  };
  auto issueB = [&](int kt) {
    const float* src = w1 + (size_t)(kt * BK + sk0) * HIDDEN + n0 + sn2;
#pragma unroll
    for (int i = 0; i < 16; ++i)
      v[i] = *(const float2*)(src + (size_t)i * HIDDEN);
  };
  auto writeB = [&](int buf) {
    ushort* base = &Bs[buf][0];
#pragma unroll
    for (int p = 0; p < 2; ++p) {
      const int n  = sn2 + p;
      const int nx = n & 7;
#pragma unroll
      for (int j = 0; j < 2; ++j) {
        float f[8];
#pragma unroll
        for (int t = 0; t < 8; ++t) f[t] = p ? v[j * 8 + t].y : v[j * 8 + t].x;
        *(short8*)(base + n * 64 + ((((wid << 1) + j) ^ nx) << 3)) = pack8(f);
      }
    }
  };
  auto compute = [&](int buf) {
    const ushort* Ab = &As[buf][0];
    const ushort* Bb = &Bs[buf][0];
#pragma unroll
    for (int ks = 0; ks < 2; ++ks) {
      const int osw = ((ks * 4 + fq) ^ x7) << 3;
      short8 af[4], bfr[4];
#pragma unroll
      for (int mi = 0; mi < 4; ++mi) {
        const int row = wm * 64 + mi * 16 + fr;
        af[mi] = *(const short8*)(Ab + row * 64 + osw);
      }
#pragma unroll
      for (int ni = 0; ni < 4; ++ni) {
        const int n = wn * 64 + ni * 16 + fr;
        bfr[ni] = *(const short8*)(Bb + n * 64 + osw);
      }
#pragma unroll
      for (int mi = 0; mi < 4; ++mi)
#pragma unroll
        for (int ni = 0; ni < 4; ++ni)
          acc[mi][ni] = __builtin_amdgcn_mfma_f32_16x16x32_bf16(
              af[mi], bfr[ni], acc[mi][ni], 0, 0, 0);
    }
  };

  issueA(kb, 0);
  issueB(kb);
  writeB(0);          // waits B regs; A (issued earlier) drained by barrier
  __syncthreads();
  int cur = 0;
  for (int kt = kb; kt < ke; ++kt) {
    const bool more = (kt + 1 < ke);
    if (more) { issueA(kt + 1, cur ^ 1); issueB(kt + 1); }  // in flight
    compute(cur);
    if (more) writeB(cur ^ 1);
    __syncthreads();
    cur ^= 1;
  }

  // epilogue: C/D mapping col = lane&15, row = (lane>>4)*4 + r  [m89-verified]
#pragma unroll
  for (int mi = 0; mi < 4; ++mi) {
#pragma unroll
    for (int ni = 0; ni < 4; ++ni) {
      const int col = n0 + wn * 64 + ni * 16 + fr;
#pragma unroll
      for (int r = 0; r < 4; ++r) {
        const int row = wm * 64 + mi * 16 + fq * 4 + r;
        if (ATOMIC) {
          atomicAdd((float*)hout_v + (size_t)row * HIDDEN + col,
                    acc[mi][ni][r]);
        } else {
          union { ushort u; __hip_bfloat16 b; } cv;
          cv.b = __float2bfloat16(acc[mi][ni][r]);
          ((ushort*)hout_v)[((size_t)g * BATCH + row) * HIDDEN + col] = cv.u;
        }
      }
    }
  }
}

// ---------------------------------------------------------------------------
// Kernel C: h = relu(sum_p parts + b1); out = log_softmax(h @ w2 + b2)
// ---------------------------------------------------------------------------
__global__ __launch_bounds__(512) void finalize_kernel(
    const ushort* __restrict__ parts, const float* __restrict__ b1,
    const float* __restrict__ w2, const float* __restrict__ b2,
    float* __restrict__ out) {
  const int b = blockIdx.x, tid = threadIdx.x;
  const int jq = tid & 127;     // j block of 8
  const int ph = tid >> 7;      // p quarter
  float h[8] = {0.f, 0.f, 0.f, 0.f, 0.f, 0.f, 0.f, 0.f};
  const ushort* src =
      parts + ((size_t)(ph * 16) * BATCH + b) * HIDDEN + jq * 8;
#pragma unroll
  for (int p = 0; p < 16; ++p) {
    short8 v = *(const short8*)(src + (size_t)p * BATCH * HIDDEN);
#pragma unroll
    for (int e = 0; e < 8; ++e) h[e] += bf2f((ushort)v[e]);
  }
  __shared__ float hp[4][HIDDEN];
  *(f32x4*)&hp[ph][jq * 8]     = (f32x4){h[0], h[1], h[2], h[3]};
  *(f32x4*)&hp[ph][jq * 8 + 4] = (f32x4){h[4], h[5], h[6], h[7]};
  __syncthreads();

  float s0 = 0.f, s1 = 0.f;
#pragma unroll
  for (int r = 0; r < 2; ++r) {
    const int j = tid * 2 + r;
    float hv = hp[0][j] + hp[1][j] + hp[2][j] + hp[3][j] + b1[j];
    hv = fmaxf(hv, 0.f);
    float2 w = *(const float2*)(w2 + 2 * j);
    s0 += hv * w.x;
    s1 += hv * w.y;
  }
#pragma unroll
  for (int off = 32; off; off >>= 1) {
    s0 += __shfl_xor(s0, off);
    s1 += __shfl_xor(s1, off);
  }
  __shared__ float r0[8], r1[8];
  if ((tid & 63) == 0) { r0[tid >> 6] = s0; r1[tid >> 6] = s1; }
  __syncthreads();
  if (tid == 0) {
    float l0 = b2[0], l1 = b2[1];
#pragma unroll
    for (int i = 0; i < 8; ++i) { l0 += r0[i]; l1 += r1[i]; }
    float mx = fmaxf(l0, l1);
    float lse = mx + logf(__expf(l0 - mx) + __expf(l1 - mx));
    out[2 * b]     = l0 - lse;
    out[2 * b + 1] = l1 - lse;
  }
}

// f32 fallback finalize (small-ws atomic path)
__global__ __launch_bounds__(256) void finalize_f32_kernel(
    const float* __restrict__ hbuf, const float* __restrict__ b1,
    const float* __restrict__ w2, const float* __restrict__ b2,
    float* __restrict__ out) {
  const int b = blockIdx.x, tid = threadIdx.x;
  const int j0 = tid * 4;
  float4 h = *(const float4*)(hbuf + ((size_t)b << 10) + j0);
  float hv0 = fmaxf(h.x + b1[j0 + 0], 0.f);
  float hv1 = fmaxf(h.y + b1[j0 + 1], 0.f);
  float hv2 = fmaxf(h.z + b1[j0 + 2], 0.f);
  float hv3 = fmaxf(h.w + b1[j0 + 3], 0.f);
  float4 wa = *(const float4*)(w2 + 2 * j0);
  float4 wb = *(const float4*)(w2 + 2 * j0 + 4);
  float s0 = hv0 * wa.x + hv1 * wa.z + hv2 * wb.x + hv3 * wb.z;
  float s1 = hv0 * wa.y + hv1 * wa.w + hv2 * wb.y + hv3 * wb.w;
#pragma unroll
  for (int off = 32; off; off >>= 1) {
    s0 += __shfl_xor(s0, off);
    s1 += __shfl_xor(s1, off);
  }
  __shared__ float r0[4], r1[4];
  if ((tid & 63) == 0) { r0[tid >> 6] = s0; r1[tid >> 6] = s1; }
  __syncthreads();
  if (tid == 0) {
    float l0 = r0[0] + r0[1] + r0[2] + r0[3] + b2[0];
    float l1 = r1[0] + r1[1] + r1[2] + r1[3] + b2[1];
    float mx = fmaxf(l0, l1);
    float lse = mx + logf(__expf(l0 - mx) + __expf(l1 - mx));
    out[2 * b]     = l0 - lse;
    out[2 * b + 1] = l1 - lse;
  }
}

__global__ __launch_bounds__(256) void zero_kernel(float4* __restrict__ p,
                                                   int n4) {
  int i = blockIdx.x * 256 + threadIdx.x;
  const int stride = gridDim.x * 256;
  for (; i < n4; i += stride) p[i] = (float4){0.f, 0.f, 0.f, 0.f};
}

// ---------------------------------------------------------------------------
extern "C" void kernel_launch(void* const* d_in, const int* in_sizes, int n_in,
                              void* d_out, int out_size, void* d_ws,
                              size_t ws_size, hipStream_t stream) {
  const int*   x      = (const int*)  d_in[0];
  const float* w_attn = (const float*)d_in[1];
  const float* b_attn = (const float*)d_in[2];
  const float* w1     = (const float*)d_in[3];
  const float* b1     = (const float*)d_in[4];
  const float* w2     = (const float*)d_in[5];
  const float* b2     = (const float*)d_in[6];
  float* out = (float*)d_out;

  const size_t pbfBytes  = (size_t)BATCH * VOCAB * sizeof(ushort);         // 8.19 MB
  const size_t partBytes = (size_t)KG * BATCH * HIDDEN * sizeof(ushort);   // 16.78 MB
  const int    ldsBytes  = VOCAB * sizeof(float);                          // 128 KB

  ushort* pooled_bf = (ushort*)d_ws;
  ushort* parts     = (ushort*)((char*)d_ws + pbfBytes);

  if (ws_size >= pbfBytes + partBytes) {
    softmax_scatter_bf<<<BATCH, 1024, ldsBytes, stream>>>(x, w_attn, b_attn,
                                                          pooled_bf);
    gemm_kernel<false><<<NT * KG, 256, 0, stream>>>(pooled_bf, w1, parts);
    finalize_kernel<<<BATCH, 512, 0, stream>>>(parts, b1, w2, b2, out);
  } else {
    float* hbuf = (float*)((char*)d_ws + pbfBytes);
    const size_t hBytes = (size_t)BATCH * HIDDEN * sizeof(float);
    zero_kernel<<<256, 256, 0, stream>>>((float4*)hbuf, (int)(hBytes / 16));
    softmax_scatter_bf<<<BATCH, 1024, ldsBytes, stream>>>(x, w_attn, b_attn,
                                                          pooled_bf);
    gemm_kernel<true><<<NT * KG, 256, 0, stream>>>(pooled_bf, w1, hbuf);
    finalize_f32_kernel<<<BATCH, 256, 0, stream>>>(hbuf, b1, w2, b2, out);
  }
}

// Round 5
// 40.825 us; speedup vs baseline: 2.1047x; 1.1005x over previous
//
#include <hip/hip_runtime.h>
#include <hip/hip_bf16.h>
#include <cstdint>
#include <cstddef>

#define VOCAB   32000
#define HIDDEN  1024
#define BATCH   128
#define SEQ     2048
#define NEG_INF -1.0e9f

#define BN 128
#define BK 64
#define NT 8      // N tiles (1024/128)
#define KG 32     // split-K groups -> 256 blocks = 1/CU exactly

typedef __attribute__((ext_vector_type(8))) short  short8;
typedef __attribute__((ext_vector_type(4))) float  f32x4;

union BF2 { __hip_bfloat162 h; uint32_t u; };
static __device__ __forceinline__ uint32_t pk2(float lo, float hi) {
  BF2 c; c.h = __float22bfloat162_rn(make_float2(lo, hi));  // v_cvt_pk_bf16_f32
  return c.u;
}
union S8U4 { short8 s; uint32_t u[4]; };
static __device__ __forceinline__ short8 pack8(const float* f) {
  S8U4 r;
  r.u[0] = pk2(f[0], f[1]); r.u[1] = pk2(f[2], f[3]);
  r.u[2] = pk2(f[4], f[5]); r.u[3] = pk2(f[6], f[7]);
  return r.s;
}
static __device__ __forceinline__ float bf2f(ushort u) {
  return __uint_as_float(((uint32_t)u) << 16);
}

typedef const uint32_t __attribute__((address_space(1))) gu32;
typedef uint32_t       __attribute__((address_space(3))) lu32;
static __device__ __forceinline__ void g2lds16(const void* g, void* l) {
  __builtin_amdgcn_global_load_lds((gu32*)g, (lu32*)l, 16, 0, 0);
}

// Raw barrier keeping N VMEM instrs in flight (T4: counted vmcnt, no drain).
#define PIPE_BARRIER(N) do {                                         \
    __builtin_amdgcn_sched_barrier(0);                               \
    asm volatile("s_waitcnt vmcnt(" #N ") lgkmcnt(0)" ::: "memory"); \
    __builtin_amdgcn_sched_barrier(0);                               \
    __builtin_amdgcn_s_barrier();                                    \
    __builtin_amdgcn_sched_barrier(0);                               \
  } while (0)

// ---------------------------------------------------------------------------
// Kernel A: fused zero + masked softmax + row-local scatter into LDS f32
// accumulator (128 KB), write out row as bf16. (unchanged from R4, verified)
// ---------------------------------------------------------------------------
__global__ __launch_bounds__(1024) void softmax_scatter_bf(
    const int* __restrict__ x, const float* __restrict__ w_attn,
    const float* __restrict__ b_attn, ushort* __restrict__ pooled_bf) {
  extern __shared__ float lds[];          // VOCAB floats
  const int b = blockIdx.x, tid = threadIdx.x;
  float4* l4 = (float4*)lds;
  for (int i = tid; i < VOCAB / 4; i += 1024)
    l4[i] = (float4){0.f, 0.f, 0.f, 0.f};

  const int* xr = x + (size_t)b * SEQ;
  const float ba = b_attn[0];
  int xi[2]; float lg[2];
  float m = -3.0e38f;
#pragma unroll
  for (int i = 0; i < 2; ++i) {
    int t = xr[tid + 1024 * i];
    xi[i] = t;
    float v = (t > 0) ? (w_attn[t] + ba) : NEG_INF;
    lg[i] = v;
    m = fmaxf(m, v);
  }
#pragma unroll
  for (int off = 32; off; off >>= 1) m = fmaxf(m, __shfl_xor(m, off));
  __shared__ float red[16], red2[16];
  if ((tid & 63) == 0) red[tid >> 6] = m;
  __syncthreads();                        // also orders zero-loop vs atomics
  float M = red[0];
#pragma unroll
  for (int i = 1; i < 16; ++i) M = fmaxf(M, red[i]);

  float e[2], s = 0.f;
#pragma unroll
  for (int i = 0; i < 2; ++i) {
    float v = (xi[i] > 0) ? __expf(lg[i] - M) : 0.f;
    e[i] = v; s += v;
  }
#pragma unroll
  for (int off = 32; off; off >>= 1) s += __shfl_xor(s, off);
  if ((tid & 63) == 0) red2[tid >> 6] = s;
  __syncthreads();
  float S = 0.f;
#pragma unroll
  for (int i = 0; i < 16; ++i) S += red2[i];
  const float inv = 1.0f / S;
#pragma unroll
  for (int i = 0; i < 2; ++i)
    if (xi[i] > 0) atomicAdd(&lds[xi[i]], e[i] * inv);   // ds_add_f32
  __syncthreads();

  ushort* pr = pooled_bf + (size_t)b * VOCAB;
  for (int i = tid; i < VOCAB / 4; i += 1024) {
    float4 v = l4[i];
    uint2 o = {pk2(v.x, v.y), pk2(v.z, v.w)};
    *(uint2*)(pr + i * 4) = o;
  }
}

// ---------------------------------------------------------------------------
// Kernel B: split-K bf16 MFMA GEMM, 128x128x64 tiles, 8 waves (2m x 4n),
// fully global_load_lds-staged, ring-3 LDS buffers, 2-tile-deep pipeline
// with counted vmcnt(6) + raw s_barrier (loads stay in flight across
// barriers). A: bf16 oct-swizzled. B: raw f32 k-major, granule-XOR swizzle
// (g ^= (k>>1)&7, 2-way conflicts = free), cvt_pk to bf16 at frag read.
// LDS: 3*16KB (A) + 3*32KB (B) = 144 KB -> 1 block/CU.
// ---------------------------------------------------------------------------
template <bool ATOMIC>
__global__ __launch_bounds__(512, 2) void gemm_kernel(
    const ushort* __restrict__ pooled_bf, const float* __restrict__ w1,
    void* __restrict__ hout_v) {
  extern __shared__ char smem[];
  ushort* As = (ushort*)smem;                       // 3 x [128][64] bf16
  float*  Bs = (float*)(smem + 3 * 16384);          // 3 x [64][128] f32

  const int tid  = threadIdx.x;
  const int lane = tid & 63;
  const int wid  = tid >> 6;
  // XCD swizzle: XCD x owns g in [x*4, x*4+4), all nt (pooled slice L2-local)
  const int id2 = (blockIdx.x & 7) * 32 + (blockIdx.x >> 3);
  const int nt  = id2 & 7;
  const int g   = id2 >> 3;
  const int n0  = nt * BN;

  int kb, ke;                       // 500 K-tiles: 20 groups of 16, 12 of 15
  if (g < 20) { kb = g * 16;              ke = kb + 16; }
  else        { kb = 320 + (g - 20) * 15; ke = kb + 15; }

  const int wm = wid >> 2, wn = wid & 3;            // 2x4 waves, 64x32 each
  const int fr = lane & 15, fq = lane >> 4;

  f32x4 acc[4][2];
#pragma unroll
  for (int i = 0; i < 4; ++i)
#pragma unroll
    for (int j = 0; j < 2; ++j) acc[i][j] = (f32x4){0.f, 0.f, 0.f, 0.f};

  // A issue: per wave 2 granules (1KB = 8 rows); source oct pre-swizzled
  const char* pbase = (const char*)pooled_bf;
  int aoff[2];
#pragma unroll
  for (int i = 0; i < 2; ++i) {
    const int row = (wid * 2 + i) * 8 + (lane >> 3);
    const int oct = (lane & 7) ^ (lane >> 3);
    aoff[i] = row * (VOCAB * 2) + oct * 16;         // bytes
  }
  // B issue: per wave 4 granules (1KB = 2 k-rows); n-granule pre-swizzled
  int bkl[4], bsn[4];
#pragma unroll
  for (int i = 0; i < 4; ++i) {
    const int kl = (wid * 4 + i) * 2 + (lane >> 5);
    bkl[i] = kl;
    bsn[i] = ((lane & 31) ^ ((kl >> 1) & 7)) * 4;   // logical n offset
  }

  auto issueA = [&](int kt, int buf) {
    char* dst = (char*)As + buf * 16384;
#pragma unroll
    for (int i = 0; i < 2; ++i)
      g2lds16(pbase + aoff[i] + kt * (BK * 2), dst + (wid * 2 + i) * 1024);
  };
  auto issueB = [&](int kt, int buf) {
    char* dst = (char*)Bs + buf * 32768;
#pragma unroll
    for (int i = 0; i < 4; ++i)
      g2lds16(w1 + (size_t)(kt * BK + bkl[i]) * HIDDEN + n0 + bsn[i],
              dst + (wid * 4 + i) * 1024);
  };
  auto compute = [&](int buf) {
    const ushort* Ab = As + buf * 8192;
    const char*   Bb = (const char*)(Bs + buf * 8192);
    short8 af[2][4], bfr[2][2];
#pragma unroll
    for (int ks = 0; ks < 2; ++ks) {
      const int osw = ((ks * 4 + fq) ^ (fr & 7)) << 3;
#pragma unroll
      for (int mi = 0; mi < 4; ++mi) {
        const int row = wm * 64 + mi * 16 + fr;
        af[ks][mi] = *(const short8*)(Ab + row * 64 + osw);
      }
    }
#pragma unroll
    for (int ni = 0; ni < 2; ++ni) {
      const int n  = wn * 32 + ni * 16 + fr;
      const int nb = ((n >> 2) << 4) | ((n & 3) << 2);
#pragma unroll
      for (int ks = 0; ks < 2; ++ks) {
        float f[8];
#pragma unroll
        for (int jp = 0; jp < 4; ++jp) {
          const int kl  = ks * 32 + fq * 8 + jp * 2;
          const int sw4 = ((kl >> 1) & 7) << 4;
          const char* p = Bb + kl * 512 + (nb ^ sw4);
          f[jp * 2]     = *(const float*)p;          // ds_read2_b32 pair
          f[jp * 2 + 1] = *(const float*)(p + 512);
        }
        bfr[ks][ni] = pack8(f);
      }
    }
#pragma unroll
    for (int ks = 0; ks < 2; ++ks)
#pragma unroll
      for (int mi = 0; mi < 4; ++mi)
#pragma unroll
        for (int ni = 0; ni < 2; ++ni)
          acc[mi][ni] = __builtin_amdgcn_mfma_f32_16x16x32_bf16(
              af[ks][mi], bfr[ks][ni], acc[mi][ni], 0, 0, 0);
  };

  // prologue: 2 tiles issued (12 VMEM/wave); retire tile kb's 6
  issueA(kb, 0);     issueB(kb, 0);
  issueA(kb + 1, 1); issueB(kb + 1, 1);
  PIPE_BARRIER(6);

  int cu = 0, is = 2;
  for (int kt = kb; kt + 2 < ke; ++kt) {
    issueA(kt + 2, is); issueB(kt + 2, is);   // 6 VMEM, in flight across 2 iters
    compute(cu);
    PIPE_BARRIER(6);                          // retire tile kt+1, keep kt+2
    cu = (cu == 2) ? 0 : cu + 1;
    is = (is == 2) ? 0 : is + 1;
  }
  compute(cu);                                // tile ke-2
  cu = (cu == 2) ? 0 : cu + 1;
  PIPE_BARRIER(0);                            // drain tile ke-1's loads
  compute(cu);                                // tile ke-1

  // epilogue: C/D mapping col = lane&15, row = (lane>>4)*4 + r  [m89-verified]
#pragma unroll
  for (int mi = 0; mi < 4; ++mi) {
#pragma unroll
    for (int ni = 0; ni < 2; ++ni) {
      const int col = n0 + wn * 32 + ni * 16 + fr;
#pragma unroll
      for (int r = 0; r < 4; ++r) {
        const int row = wm * 64 + mi * 16 + fq * 4 + r;
        if (ATOMIC) {
          atomicAdd((float*)hout_v + (size_t)row * HIDDEN + col,
                    acc[mi][ni][r]);
        } else {
          union { ushort u; __hip_bfloat16 b; } cv;
          cv.b = __float2bfloat16(acc[mi][ni][r]);
          ((ushort*)hout_v)[((size_t)g * BATCH + row) * HIDDEN + col] = cv.u;
        }
      }
    }
  }
}

// ---------------------------------------------------------------------------
// Kernel C: h = relu(sum_p parts + b1); out = log_softmax(h @ w2 + b2)
// ---------------------------------------------------------------------------
__global__ __launch_bounds__(512) void finalize_kernel(
    const ushort* __restrict__ parts, const float* __restrict__ b1,
    const float* __restrict__ w2, const float* __restrict__ b2,
    float* __restrict__ out) {
  const int b = blockIdx.x, tid = threadIdx.x;
  const int jq = tid & 127;     // j block of 8
  const int ph = tid >> 7;      // p quarter (8 each, KG=32)
  float h[8] = {0.f, 0.f, 0.f, 0.f, 0.f, 0.f, 0.f, 0.f};
  const ushort* src =
      parts + ((size_t)(ph * 8) * BATCH + b) * HIDDEN + jq * 8;
#pragma unroll
  for (int p = 0; p < 8; ++p) {
    short8 v = *(const short8*)(src + (size_t)p * BATCH * HIDDEN);
#pragma unroll
    for (int e = 0; e < 8; ++e) h[e] += bf2f((ushort)v[e]);
  }
  __shared__ float hp[4][HIDDEN];
  *(f32x4*)&hp[ph][jq * 8]     = (f32x4){h[0], h[1], h[2], h[3]};
  *(f32x4*)&hp[ph][jq * 8 + 4] = (f32x4){h[4], h[5], h[6], h[7]};
  __syncthreads();

  float s0 = 0.f, s1 = 0.f;
#pragma unroll
  for (int r = 0; r < 2; ++r) {
    const int j = tid * 2 + r;
    float hv = hp[0][j] + hp[1][j] + hp[2][j] + hp[3][j] + b1[j];
    hv = fmaxf(hv, 0.f);
    float2 w = *(const float2*)(w2 + 2 * j);
    s0 += hv * w.x;
    s1 += hv * w.y;
  }
#pragma unroll
  for (int off = 32; off; off >>= 1) {
    s0 += __shfl_xor(s0, off);
    s1 += __shfl_xor(s1, off);
  }
  __shared__ float r0[8], r1[8];
  if ((tid & 63) == 0) { r0[tid >> 6] = s0; r1[tid >> 6] = s1; }
  __syncthreads();
  if (tid == 0) {
    float l0 = b2[0], l1 = b2[1];
#pragma unroll
    for (int i = 0; i < 8; ++i) { l0 += r0[i]; l1 += r1[i]; }
    float mx = fmaxf(l0, l1);
    float lse = mx + logf(__expf(l0 - mx) + __expf(l1 - mx));
    out[2 * b]     = l0 - lse;
    out[2 * b + 1] = l1 - lse;
  }
}

// f32 fallback finalize (small-ws atomic path)
__global__ __launch_bounds__(256) void finalize_f32_kernel(
    const float* __restrict__ hbuf, const float* __restrict__ b1,
    const float* __restrict__ w2, const float* __restrict__ b2,
    float* __restrict__ out) {
  const int b = blockIdx.x, tid = threadIdx.x;
  const int j0 = tid * 4;
  float4 h = *(const float4*)(hbuf + ((size_t)b << 10) + j0);
  float hv0 = fmaxf(h.x + b1[j0 + 0], 0.f);
  float hv1 = fmaxf(h.y + b1[j0 + 1], 0.f);
  float hv2 = fmaxf(h.z + b1[j0 + 2], 0.f);
  float hv3 = fmaxf(h.w + b1[j0 + 3], 0.f);
  float4 wa = *(const float4*)(w2 + 2 * j0);
  float4 wb = *(const float4*)(w2 + 2 * j0 + 4);
  float s0 = hv0 * wa.x + hv1 * wa.z + hv2 * wb.x + hv3 * wb.z;
  float s1 = hv0 * wa.y + hv1 * wa.w + hv2 * wb.y + hv3 * wb.w;
#pragma unroll
  for (int off = 32; off; off >>= 1) {
    s0 += __shfl_xor(s0, off);
    s1 += __shfl_xor(s1, off);
  }
  __shared__ float r0[4], r1[4];
  if ((tid & 63) == 0) { r0[tid >> 6] = s0; r1[tid >> 6] = s1; }
  __syncthreads();
  if (tid == 0) {
    float l0 = r0[0] + r0[1] + r0[2] + r0[3] + b2[0];
    float l1 = r1[0] + r1[1] + r1[2] + r1[3] + b2[1];
    float mx = fmaxf(l0, l1);
    float lse = mx + logf(__expf(l0 - mx) + __expf(l1 - mx));
    out[2 * b]     = l0 - lse;
    out[2 * b + 1] = l1 - lse;
  }
}

__global__ __launch_bounds__(256) void zero_kernel(float4* __restrict__ p,
                                                   int n4) {
  int i = blockIdx.x * 256 + threadIdx.x;
  const int stride = gridDim.x * 256;
  for (; i < n4; i += stride) p[i] = (float4){0.f, 0.f, 0.f, 0.f};
}

// ---------------------------------------------------------------------------
extern "C" void kernel_launch(void* const* d_in, const int* in_sizes, int n_in,
                              void* d_out, int out_size, void* d_ws,
                              size_t ws_size, hipStream_t stream) {
  const int*   x      = (const int*)  d_in[0];
  const float* w_attn = (const float*)d_in[1];
  const float* b_attn = (const float*)d_in[2];
  const float* w1     = (const float*)d_in[3];
  const float* b1     = (const float*)d_in[4];
  const float* w2     = (const float*)d_in[5];
  const float* b2     = (const float*)d_in[6];
  float* out = (float*)d_out;

  const size_t pbfBytes  = (size_t)BATCH * VOCAB * sizeof(ushort);        // 8.19 MB
  const size_t partBytes = (size_t)KG * BATCH * HIDDEN * sizeof(ushort);  // 8.39 MB
  const int    ldsA      = VOCAB * sizeof(float);                         // 128 KB
  const int    ldsG      = 3 * 16384 + 3 * 32768;                         // 144 KB

  ushort* pooled_bf = (ushort*)d_ws;
  ushort* parts     = (ushort*)((char*)d_ws + pbfBytes);

  if (ws_size >= pbfBytes + partBytes) {
    softmax_scatter_bf<<<BATCH, 1024, ldsA, stream>>>(x, w_attn, b_attn,
                                                      pooled_bf);
    gemm_kernel<false><<<NT * KG, 512, ldsG, stream>>>(pooled_bf, w1, parts);
    finalize_kernel<<<BATCH, 512, 0, stream>>>(parts, b1, w2, b2, out);
  } else {
    float* hbuf = (float*)((char*)d_ws + pbfBytes);
    const size_t hBytes = (size_t)BATCH * HIDDEN * sizeof(float);
    zero_kernel<<<256, 256, 0, stream>>>((float4*)hbuf, (int)(hBytes / 16));
    softmax_scatter_bf<<<BATCH, 1024, ldsA, stream>>>(x, w_attn, b_attn,
                                                      pooled_bf);
    gemm_kernel<true><<<NT * KG, 512, ldsG, stream>>>(pooled_bf, w1, hbuf);
    finalize_f32_kernel<<<BATCH, 256, 0, stream>>>(hbuf, b1, w2, b2, out);
  }
}